// Round 2
// baseline (2326.015 us; speedup 1.0000x reference)
//
#include <hip/hip_runtime.h>
#include <math.h>
#include <float.h>
#include <limits.h>

#define N_TOT   16384
#define DIM     256
#define KCB     8192
#define LSEQ    2048
#define BN      64
#define BK      64
#define DCH     128
#define ZPAD    4
#define EPAD    4
#define TAU2    5e-5f
#define FR      8

// ws layout:
// [0,64KB)        sz    float[16384]   (np-replica fp32 row norms)
// [64KB,128KB)    idx   int[16384]
// [128KB,192KB)   flag  int[16384]
// [192KB,256KB)   list  int[16384]
// [256KB,+4)      cnt   int
// [260KB,+1KB)    part  float[256]

// Bit-exact replica of np.sum(x**2, axis=1) fp32 pairwise for n=256:
// pairwise(256) = base128(x[0:128]) + base128(x[128:256]);
// base128: r[j]=x[j]; for i=8..120 step 8: r[j]+=x[i+j];
//          res=((r0+r1)+(r2+r3))+((r4+r5)+(r6+r7)).
__global__ __launch_bounds__(256) void k_sz(const float* __restrict__ z,
                                            float* __restrict__ sz) {
  int n = blockIdx.x * 256 + threadIdx.x;
  int b = n >> 11, l = n & (LSEQ - 1);
  const float* zp = z + (size_t)b * DIM * LSEQ + l;
  float h[2];
  #pragma unroll
  for (int half = 0; half < 2; ++half) {
    int d0 = half * 128;
    float r[8];
    #pragma unroll
    for (int j = 0; j < 8; ++j) {
      float v = zp[(size_t)(d0 + j) * LSEQ];
      r[j] = __fmul_rn(v, v);
    }
    #pragma unroll
    for (int i = 8; i < 128; i += 8) {
      #pragma unroll
      for (int j = 0; j < 8; ++j) {
        float v = zp[(size_t)(d0 + i + j) * LSEQ];
        r[j] = __fadd_rn(r[j], __fmul_rn(v, v));
      }
    }
    h[half] = __fadd_rn(__fadd_rn(__fadd_rn(r[0], r[1]), __fadd_rn(r[2], r[3])),
                        __fadd_rn(__fadd_rn(r[4], r[5]), __fadd_rn(r[6], r[7])));
  }
  sz[n] = __fadd_rn(h[0], h[1]);
}

// fp32 GEMM top-2 over x~ = -2*dot (row-constant sz irrelevant for ordering).
// Rows whose top-2 gap < TAU2 are flagged for exact fixup.
__global__ __launch_bounds__(256) void k_argmin(const float* __restrict__ z,
                                                const float* __restrict__ emb,
                                                int* __restrict__ idx_out,
                                                int* __restrict__ flag_out) {
  __shared__ float zt[DCH][BN + ZPAD];     // [d-chunk][row]
  __shared__ float et[BK][DCH + EPAD];     // [code][d-chunk]

  const int tid = threadIdx.x;
  const int n0 = blockIdx.x * BN;
  const int b  = n0 >> 11;
  const int l0 = n0 & (LSEQ - 1);
  const size_t zbase = (size_t)b * DIM * LSEQ + l0;

  const int tn = tid >> 4;   // row group 0..15 (rows tn*4..tn*4+3)
  const int tk = tid & 15;   // code group 0..15 (codes tk+16j)

  const int z_dgrp = tid >> 4, z_lq = tid & 15;
  const int e_kk   = tid >> 2, e_fq = tid & 3;

  float s1[4], s2[4]; int i1[4];
  #pragma unroll
  for (int i = 0; i < 4; ++i) { s1[i] = FLT_MAX; s2[i] = FLT_MAX; i1[i] = 0; }

  for (int k0 = 0; k0 < KCB; k0 += BK) {
    float acc[4][4];
    #pragma unroll
    for (int i = 0; i < 4; ++i)
      #pragma unroll
      for (int j = 0; j < 4; ++j) acc[i][j] = 0.f;

    for (int d0 = 0; d0 < DIM; d0 += DCH) {
      __syncthreads();
      #pragma unroll
      for (int it = 0; it < 8; ++it) {     // stage z chunk [128][64]
        int dl = z_dgrp + it * 16;
        float4 v = *(const float4*)&z[zbase + (size_t)(d0 + dl) * LSEQ + z_lq * 4];
        *(float4*)&zt[dl][z_lq * 4] = v;
      }
      #pragma unroll
      for (int it = 0; it < 8; ++it) {     // stage emb chunk [64][128]
        int dq = e_fq + it * 4;
        float4 v = *(const float4*)&emb[(size_t)(k0 + e_kk) * DIM + d0 + dq * 4];
        *(float4*)&et[e_kk][dq * 4] = v;
      }
      __syncthreads();

      #pragma unroll 4
      for (int dd = 0; dd < DCH; dd += 4) {
        float za[4][4], eb[4][4];
        #pragma unroll
        for (int q = 0; q < 4; ++q) {
          float4 t = *(const float4*)&zt[dd + q][tn * 4];
          za[q][0] = t.x; za[q][1] = t.y; za[q][2] = t.z; za[q][3] = t.w;
        }
        #pragma unroll
        for (int j = 0; j < 4; ++j) {
          float4 t = *(const float4*)&et[tk + 16 * j][dd];
          eb[j][0] = t.x; eb[j][1] = t.y; eb[j][2] = t.z; eb[j][3] = t.w;
        }
        #pragma unroll
        for (int j = 0; j < 4; ++j)
          #pragma unroll
          for (int q = 0; q < 4; ++q)
            #pragma unroll
            for (int i = 0; i < 4; ++i)
              acc[i][j] = fmaf(za[q][i], eb[j][q], acc[i][j]);
      }
    }

    // top-2 update; x~ = -2*acc (exact scaling, preserves ordering)
    #pragma unroll
    for (int j = 0; j < 4; ++j) {
      int k = k0 + tk + 16 * j;
      #pragma unroll
      for (int i = 0; i < 4; ++i) {
        float s = __fmul_rn(-2.f, acc[i][j]);
        if (s < s1[i]) { s2[i] = s1[i]; s1[i] = s; i1[i] = k; }
        else           { s2[i] = fminf(s2[i], s); }
      }
    }
  }

  // merge across the 16 tk-lanes sharing the same rows
  #pragma unroll
  for (int off = 1; off < 16; off <<= 1) {
    #pragma unroll
    for (int i = 0; i < 4; ++i) {
      float os1 = __shfl_xor(s1[i], off, 64);
      float os2 = __shfl_xor(s2[i], off, 64);
      int   oi1 = __shfl_xor(i1[i], off, 64);
      if (os1 < s1[i] || (os1 == s1[i] && oi1 < i1[i])) {
        s2[i] = fminf(s1[i], os2);
        s1[i] = os1; i1[i] = oi1;
      } else {
        s2[i] = fminf(s2[i], os1);
      }
    }
  }
  if (tk == 0) {
    #pragma unroll
    for (int i = 0; i < 4; ++i) {
      int n = n0 + tn * 4 + i;
      idx_out[n]  = i1[i];
      flag_out[n] = (s2[i] - s1[i] < TAU2) ? 1 : 0;
    }
  }
}

__global__ void k_zero(int* cnt) { *cnt = 0; }

__global__ __launch_bounds__(256) void k_compact(const int* __restrict__ flag,
                                                 int* __restrict__ list,
                                                 int* __restrict__ cnt) {
  int n = blockIdx.x * 256 + threadIdx.x;
  if (flag[n]) { int p = atomicAdd(cnt, 1); list[p] = n; }
}

// Exact replica rescan of flagged rows: D_k = RN32(sz - 2*RN32(dot_f64)),
// argmin over fp32 bits with first-index tie-break (== np.argmin on the
// fp32 distance row, since the +sz quantization is reproduced exactly).
__global__ __launch_bounds__(256) void k_fix(const float* __restrict__ z,
                                             const float* __restrict__ emb,
                                             const float* __restrict__ szt,
                                             const int* __restrict__ list,
                                             const int* __restrict__ cnt,
                                             int* __restrict__ idx) {
  __shared__ float zs[FR][DIM];
  __shared__ float szr[FR];
  __shared__ float redD[FR][4];
  __shared__ int   redK[FR][4];
  const int tid = threadIdx.x;
  const int nf = *cnt;
  for (int base = blockIdx.x * FR; base < nf; base += gridDim.x * FR) {
    const int nr = min(FR, nf - base);
    for (int i = 0; i < nr; ++i) {
      int n = list[base + i];
      int b = n >> 11, l = n & (LSEQ - 1);
      zs[i][tid] = z[(size_t)b * DIM * LSEQ + (size_t)tid * LSEQ + l];
    }
    if (tid < nr) szr[tid] = szt[list[base + tid]];
    __syncthreads();

    float bD[FR]; int bK[FR];
    #pragma unroll
    for (int i = 0; i < FR; ++i) { bD[i] = FLT_MAX; bK[i] = INT_MAX; }

    for (int kb = 0; kb < KCB / 256; ++kb) {
      int k = kb * 256 + tid;
      const float* er = emb + (size_t)k * DIM;
      double dot[FR];
      #pragma unroll
      for (int i = 0; i < FR; ++i) dot[i] = 0.0;
      for (int d = 0; d < DIM; ++d) {
        double e = (double)er[d];
        #pragma unroll
        for (int i = 0; i < FR; ++i) dot[i] = fma(e, (double)zs[i][d], dot[i]);
      }
      #pragma unroll
      for (int i = 0; i < FR; ++i) {
        float D = __fsub_rn(szr[i], __fmul_rn(2.f, (float)dot[i]));
        if (D < bD[i] || (D == bD[i] && k < bK[i])) { bD[i] = D; bK[i] = k; }
      }
    }

    for (int i = 0; i < nr; ++i) {
      float D = bD[i]; int K = bK[i];
      #pragma unroll
      for (int off = 1; off < 64; off <<= 1) {
        float oD = __shfl_xor(D, off, 64);
        int   oK = __shfl_xor(K, off, 64);
        if (oD < D || (oD == D && oK < K)) { D = oD; K = oK; }
      }
      if ((tid & 63) == 0) { redD[i][tid >> 6] = D; redK[i][tid >> 6] = K; }
    }
    __syncthreads();
    if (tid < nr) {
      float D = redD[tid][0]; int K = redK[tid][0];
      #pragma unroll
      for (int w = 1; w < 4; ++w)
        if (redD[tid][w] < D || (redD[tid][w] == D && redK[tid][w] < K)) {
          D = redD[tid][w]; K = redK[tid][w];
        }
      idx[list[base + tid]] = K;
    }
    __syncthreads();
  }
}

__global__ __launch_bounds__(256) void k_gather(const float* __restrict__ z,
                                                const float* __restrict__ emb,
                                                const int* __restrict__ idx,
                                                float* __restrict__ zq_out,
                                                float* __restrict__ idxf_out,
                                                float* __restrict__ partial) {
  __shared__ int il[BN];
  __shared__ float red[4];
  const int tid = threadIdx.x;
  const int n0 = blockIdx.x * BN;
  const int b = n0 >> 11, l0 = n0 & (LSEQ - 1);
  if (tid < BN) {
    int v = idx[n0 + tid];
    il[tid] = v;
    idxf_out[n0 + tid] = (float)v;
  }
  __syncthreads();
  const int dgrp = tid >> 6;
  const int lo   = tid & 63;
  const size_t zb = (size_t)b * DIM * LSEQ + l0 + lo;
  const int myidx = il[lo];
  float acc = 0.f;
  #pragma unroll 4
  for (int dd = 0; dd < 64; ++dd) {
    int d = dgrp + dd * 4;
    float e  = emb[(size_t)myidx * DIM + d];
    float zv = z[zb + (size_t)d * LSEQ];
    zq_out[zb + (size_t)d * LSEQ] = e;    // out layout == z layout
    float df = e - zv;
    acc = fmaf(df, df, acc);
  }
  #pragma unroll
  for (int off = 1; off < 64; off <<= 1) acc += __shfl_xor(acc, off, 64);
  if ((tid & 63) == 0) red[tid >> 6] = acc;
  __syncthreads();
  if (tid == 0) partial[blockIdx.x] = red[0] + red[1] + red[2] + red[3];
}

__global__ __launch_bounds__(256) void k_loss(const float* __restrict__ partial,
                                              float* __restrict__ out_loss) {
  const int tid = threadIdx.x;
  double a = (double)partial[tid];
  #pragma unroll
  for (int off = 1; off < 64; off <<= 1) a += __shfl_xor(a, off, 64);
  __shared__ double r[4];
  if ((tid & 63) == 0) r[tid >> 6] = a;
  __syncthreads();
  if (tid == 0) {
    double s = r[0] + r[1] + r[2] + r[3];
    out_loss[0] = (float)(1.25 * s / (double)((size_t)N_TOT * DIM));
  }
}

extern "C" void kernel_launch(void* const* d_in, const int* in_sizes, int n_in,
                              void* d_out, int out_size, void* d_ws, size_t ws_size,
                              hipStream_t stream) {
  const float* z   = (const float*)d_in[0];
  const float* emb = (const float*)d_in[1];
  float* out = (float*)d_out;
  char* ws = (char*)d_ws;
  float* sz   = (float*)ws;
  int*   idx  = (int*)(ws + (64 << 10));
  int*   flag = (int*)(ws + (128 << 10));
  int*   list = (int*)(ws + (192 << 10));
  int*   cnt  = (int*)(ws + (256 << 10));
  float* part = (float*)(ws + (260 << 10));

  float* zq_out   = out;
  float* loss_out = out + (size_t)N_TOT * DIM;
  float* idxf_out = out + (size_t)N_TOT * DIM + 1;

  k_zero   <<<1,          1,   0, stream>>>(cnt);
  k_sz     <<<N_TOT/256,  256, 0, stream>>>(z, sz);
  k_argmin <<<N_TOT/BN,   256, 0, stream>>>(z, emb, idx, flag);
  k_compact<<<N_TOT/256,  256, 0, stream>>>(flag, list, cnt);
  k_fix    <<<128,        256, 0, stream>>>(z, emb, sz, list, cnt, idx);
  k_gather <<<N_TOT/BN,   256, 0, stream>>>(z, emb, idx, zq_out, idxf_out, part);
  k_loss   <<<1,          256, 0, stream>>>(part, loss_out);
}

// Round 3
// 554.302 us; speedup vs baseline: 4.1963x; 4.1963x over previous
//
#include <hip/hip_runtime.h>
#include <hip/hip_bf16.h>
#include <math.h>
#include <float.h>
#include <limits.h>

#define N_TOT   16384
#define DIM     256
#define KCB     8192
#define LSEQ    2048
#define TAU_A   1.8e-5f
#define FR      4

typedef unsigned short u16;
typedef unsigned int   u32;
typedef __attribute__((ext_vector_type(8))) short bf16x8;
typedef __attribute__((ext_vector_type(4))) float f32x4;

// ws layout (bytes)
#define WS_ZT_HI 0u
#define WS_ZT_LO 8388608u
#define WS_E_HI  16777216u
#define WS_E_LO  20971520u
#define WS_SZ    25165824u
#define WS_IDX   25231360u
#define WS_FLAG  25296896u
#define WS_LIST  25362432u
#define WS_CNT   25427968u
#define WS_PART  25428992u
#define WS_PA1   25430016u
#define WS_PA2   25561088u
#define WS_PI1   25692160u

__device__ __forceinline__ u16 f2bf_bits(float x) {
  __hip_bfloat16 h = __float2bfloat16(x);
  return *reinterpret_cast<u16*>(&h);
}
__device__ __forceinline__ float bfbits2f(u16 b) {
  __hip_bfloat16 h = *reinterpret_cast<__hip_bfloat16*>(&b);
  return __bfloat162float(h);
}

__device__ __forceinline__ void gl_lds16(const void* g, void* l) {
  __builtin_amdgcn_global_load_lds(
      (const __attribute__((address_space(1))) u32*)g,
      (__attribute__((address_space(3))) u32*)l, 16, 0, 0);
}

// ---------- split z [b][d][l] -> zt_hi/zt_lo [n][d] bf16 ----------
__global__ __launch_bounds__(256) void k_split_z(const float* __restrict__ z,
                                                 u16* __restrict__ zhi,
                                                 u16* __restrict__ zlo) {
  int bidx = blockIdx.x;                 // 8 b * 4 dt * 32 lt = 1024
  int lt = bidx & 31, dt = (bidx >> 5) & 3, bb = bidx >> 7;
  int ll = threadIdx.x & 63, dg = threadIdx.x >> 6;
  int l = lt * 64 + ll, d0 = dt * 64 + dg * 16;
  int n = bb * LSEQ + l;
  const float* zp = z + (size_t)bb * DIM * LSEQ + (size_t)d0 * LSEQ + l;
  u32 hw[8], lw[8];
  #pragma unroll
  for (int j = 0; j < 16; ++j) {
    float v = zp[(size_t)j * LSEQ];
    u16 hb = f2bf_bits(v);
    float hf = bfbits2f(hb);
    u16 lb = f2bf_bits(v - hf);
    if (j & 1) { hw[j >> 1] |= (u32)hb << 16; lw[j >> 1] |= (u32)lb << 16; }
    else       { hw[j >> 1]  = hb;            lw[j >> 1]  = lb; }
  }
  size_t o = (size_t)n * DIM + d0;
  *(uint4*)(zhi + o)     = make_uint4(hw[0], hw[1], hw[2], hw[3]);
  *(uint4*)(zhi + o + 8) = make_uint4(hw[4], hw[5], hw[6], hw[7]);
  *(uint4*)(zlo + o)     = make_uint4(lw[0], lw[1], lw[2], lw[3]);
  *(uint4*)(zlo + o + 8) = make_uint4(lw[4], lw[5], lw[6], lw[7]);
}

// ---------- split emb [k][d] -> e_hi/e_lo bf16 ----------
__global__ __launch_bounds__(256) void k_split_e(const float* __restrict__ emb,
                                                 u16* __restrict__ ehi,
                                                 u16* __restrict__ elo) {
  int g = blockIdx.x * 256 + threadIdx.x;   // 2048 blocks, 4 floats each
  float4 v = ((const float4*)emb)[g];
  u16 h0 = f2bf_bits(v.x), h1 = f2bf_bits(v.y), h2 = f2bf_bits(v.z), h3 = f2bf_bits(v.w);
  u16 l0 = f2bf_bits(v.x - bfbits2f(h0));
  u16 l1 = f2bf_bits(v.y - bfbits2f(h1));
  u16 l2 = f2bf_bits(v.z - bfbits2f(h2));
  u16 l3 = f2bf_bits(v.w - bfbits2f(h3));
  ((uint2*)ehi)[g] = make_uint2((u32)h0 | ((u32)h1 << 16), (u32)h2 | ((u32)h3 << 16));
  ((uint2*)elo)[g] = make_uint2((u32)l0 | ((u32)l1 << 16), (u32)l2 | ((u32)l3 << 16));
}

// ---------- np-replica fp32 pairwise row norms (unchanged, verified) ----------
__global__ __launch_bounds__(256) void k_sz(const float* __restrict__ z,
                                            float* __restrict__ sz) {
  int n = blockIdx.x * 256 + threadIdx.x;
  int b = n >> 11, l = n & (LSEQ - 1);
  const float* zp = z + (size_t)b * DIM * LSEQ + l;
  float h[2];
  #pragma unroll
  for (int half = 0; half < 2; ++half) {
    int d0 = half * 128;
    float r[8];
    #pragma unroll
    for (int j = 0; j < 8; ++j) {
      float v = zp[(size_t)(d0 + j) * LSEQ];
      r[j] = __fmul_rn(v, v);
    }
    #pragma unroll
    for (int i = 8; i < 128; i += 8) {
      #pragma unroll
      for (int j = 0; j < 8; ++j) {
        float v = zp[(size_t)(d0 + i + j) * LSEQ];
        r[j] = __fadd_rn(r[j], __fmul_rn(v, v));
      }
    }
    h[half] = __fadd_rn(__fadd_rn(__fadd_rn(r[0], r[1]), __fadd_rn(r[2], r[3])),
                        __fadd_rn(__fadd_rn(r[4], r[5]), __fadd_rn(r[6], r[7])));
  }
  sz[n] = __fadd_rn(h[0], h[1]);
}

// ---------- MFMA top-2 phase-1 ----------
// grid 256 = 128 row-blocks x 2 code-halves; 512 threads (8 waves, 2 wr x 4 wc)
// block tile 128 rows x 128 codes, d-phases of 64, double-buffered 128KB LDS.
__global__ __launch_bounds__(512) void k_mfma(const u16* __restrict__ zhi_g,
                                              const u16* __restrict__ zlo_g,
                                              const u16* __restrict__ ehi_g,
                                              const u16* __restrict__ elo_g,
                                              float* __restrict__ pa1,
                                              float* __restrict__ pa2,
                                              int* __restrict__ pi1) {
  extern __shared__ char smem[];
  const int tid = threadIdx.x;
  const int lane = tid & 63, w = tid >> 6;
  const int wr = w >> 2, wc = w & 3;
  const int bid = blockIdx.x;
  const int half = bid & 1;
  const int rb = (bid >> 1) * 128;
  const size_t zrow0 = (size_t)rb * 512;                 // byte offset of block's z rows
  const size_t ecol0 = (size_t)half * 4096 * 512;        // byte offset of code half
  // per-lane pre-swizzled source offset (inverse of XOR read swizzle)
  const int srcoff = ((lane >> 3) << 9) + ((((lane & 7) ^ ((lane >> 3) & 7))) << 4);
  const int arr = w >> 1;                                 // 0 zhi, 1 zlo, 2 ehi, 3 elo
  const char* gbase = (arr == 0) ? (const char*)zhi_g + zrow0
                    : (arr == 1) ? (const char*)zlo_g + zrow0
                    : (arr == 2) ? (const char*)ehi_g + ecol0
                                 : (const char*)elo_g + ecol0;
  const bool is_e = (arr >= 2);
  const int i0 = (w & 1) * 8;

  f32x4 acc[4][2];
  #pragma unroll
  for (int rc = 0; rc < 4; ++rc)
    #pragma unroll
    for (int cc = 0; cc < 2; ++cc) acc[rc][cc] = (f32x4){0.f, 0.f, 0.f, 0.f};

  float a1[4], a2[4]; int i1[4];
  #pragma unroll
  for (int rc = 0; rc < 4; ++rc) { a1[rc] = -FLT_MAX; a2[rc] = -FLT_MAX; i1[rc] = 0; }

  // frag read bases (byte offsets within a 16KB array tile)
  int rbyte[4], cbyte[2];
  #pragma unroll
  for (int rc = 0; rc < 4; ++rc) rbyte[rc] = (wr * 64 + rc * 16 + (lane & 15)) * 128;
  #pragma unroll
  for (int cc = 0; cc < 2; ++cc) cbyte[cc] = (wc * 32 + cc * 16 + (lane & 15)) * 128;

  #define STAGE(P) {                                                        \
    int dq_ = (P) & 3, t_ = (P) >> 2;                                       \
    char* buf_ = smem + (((P) & 1) << 16) + arr * 16384;                    \
    const char* s0_ = gbase + (is_e ? (size_t)t_ * 65536 : (size_t)0)       \
                            + dq_ * 128 + srcoff;                           \
    _Pragma("unroll")                                                       \
    for (int j_ = 0; j_ < 8; ++j_) {                                        \
      int i_ = i0 + j_;                                                     \
      gl_lds16(s0_ + (size_t)i_ * 4096, buf_ + i_ * 1024);                  \
    }                                                                       \
  }

  STAGE(0);
  __syncthreads();

  for (int p = 0; p < 128; ++p) {
    if (p + 1 < 128) STAGE(p + 1);
    const char* b0 = smem + ((p & 1) << 16);
    const char* bzh = b0;
    const char* bzl = b0 + 16384;
    const char* beh = b0 + 32768;
    const char* bel = b0 + 49152;
    #pragma unroll
    for (int kc = 0; kc < 2; ++kc) {
      int coff = ((kc * 4 + (lane >> 4)) ^ (lane & 7)) << 4;
      bf16x8 bh[4], bl[4], ah[2], al[2];
      #pragma unroll
      for (int rc = 0; rc < 4; ++rc) {
        bh[rc] = *(const bf16x8*)(bzh + rbyte[rc] + coff);
        bl[rc] = *(const bf16x8*)(bzl + rbyte[rc] + coff);
      }
      #pragma unroll
      for (int cc = 0; cc < 2; ++cc) {
        ah[cc] = *(const bf16x8*)(beh + cbyte[cc] + coff);
        al[cc] = *(const bf16x8*)(bel + cbyte[cc] + coff);
      }
      #pragma unroll
      for (int rc = 0; rc < 4; ++rc)
        #pragma unroll
        for (int cc = 0; cc < 2; ++cc) {
          acc[rc][cc] = __builtin_amdgcn_mfma_f32_16x16x32_bf16(ah[cc], bh[rc], acc[rc][cc], 0, 0, 0);
          acc[rc][cc] = __builtin_amdgcn_mfma_f32_16x16x32_bf16(ah[cc], bl[rc], acc[rc][cc], 0, 0, 0);
          acc[rc][cc] = __builtin_amdgcn_mfma_f32_16x16x32_bf16(al[cc], bh[rc], acc[rc][cc], 0, 0, 0);
        }
    }
    if ((p & 3) == 3) {           // end of one 128-code k0-tile: top-2 update
      int t = p >> 2;
      int cbase = half * 4096 + t * 128 + wc * 32 + (lane >> 4) * 4;
      #pragma unroll
      for (int rc = 0; rc < 4; ++rc)
        #pragma unroll
        for (int cc = 0; cc < 2; ++cc) {
          #pragma unroll
          for (int r = 0; r < 4; ++r) {
            float v = acc[rc][cc][r];
            int code = cbase + cc * 16 + r;
            if (v > a1[rc]) { a2[rc] = a1[rc]; a1[rc] = v; i1[rc] = code; }
            else            { a2[rc] = fmaxf(a2[rc], v); }
          }
          acc[rc][cc] = (f32x4){0.f, 0.f, 0.f, 0.f};
        }
    }
    __syncthreads();
  }
  #undef STAGE

  // merge the 4 lane-groups (lane^16, lane^32) holding the same row
  #pragma unroll
  for (int rc = 0; rc < 4; ++rc) {
    #pragma unroll
    for (int off = 16; off < 64; off <<= 1) {
      float o1 = __shfl_xor(a1[rc], off, 64);
      float o2 = __shfl_xor(a2[rc], off, 64);
      int   oi = __shfl_xor(i1[rc], off, 64);
      if (o1 > a1[rc] || (o1 == a1[rc] && oi < i1[rc])) {
        a2[rc] = fmaxf(a1[rc], o2); a1[rc] = o1; i1[rc] = oi;
      } else {
        a2[rc] = fmaxf(a2[rc], o1);
      }
    }
  }
  // cross-wave (wc) merge via LDS
  float* sa1 = (float*)smem;            // [4][128]
  float* sa2 = sa1 + 512;
  int*   si1 = (int*)(sa2 + 512);
  if ((lane >> 4) == 0) {
    #pragma unroll
    for (int rc = 0; rc < 4; ++rc) {
      int rl = wr * 64 + rc * 16 + lane;
      sa1[wc * 128 + rl] = a1[rc];
      sa2[wc * 128 + rl] = a2[rc];
      si1[wc * 128 + rl] = i1[rc];
    }
  }
  __syncthreads();
  if (tid < 128) {
    float g1 = sa1[tid], g2 = sa2[tid]; int gi = si1[tid];
    #pragma unroll
    for (int q = 1; q < 4; ++q) {
      float o1 = sa1[q * 128 + tid], o2 = sa2[q * 128 + tid]; int oi = si1[q * 128 + tid];
      if (o1 > g1 || (o1 == g1 && oi < gi)) { g2 = fmaxf(g1, o2); g1 = o1; gi = oi; }
      else { g2 = fmaxf(g2, o1); }
    }
    int n = rb + tid;
    pa1[half * N_TOT + n] = g1;
    pa2[half * N_TOT + n] = g2;
    pi1[half * N_TOT + n] = gi;
  }
}

// ---------- merge the two code-halves; emit idx + near-tie flag ----------
__global__ __launch_bounds__(256) void k_merge(const float* __restrict__ pa1,
                                               const float* __restrict__ pa2,
                                               const int* __restrict__ pi1,
                                               int* __restrict__ idx,
                                               int* __restrict__ flag) {
  int n = blockIdx.x * 256 + threadIdx.x;
  float g1 = pa1[n], g2 = pa2[n]; int gi = pi1[n];
  float o1 = pa1[N_TOT + n], o2 = pa2[N_TOT + n]; int oi = pi1[N_TOT + n];
  if (o1 > g1 || (o1 == g1 && oi < gi)) { g2 = fmaxf(g1, o2); g1 = o1; gi = oi; }
  else { g2 = fmaxf(g2, o1); }
  idx[n] = gi;
  flag[n] = (g1 - g2 < TAU_A) ? 1 : 0;
}

__global__ void k_zero(int* cnt) { *cnt = 0; }

__global__ __launch_bounds__(256) void k_compact(const int* __restrict__ flag,
                                                 int* __restrict__ list,
                                                 int* __restrict__ cnt) {
  int n = blockIdx.x * 256 + threadIdx.x;
  if (flag[n]) { int p = atomicAdd(cnt, 1); list[p] = n; }
}

// ---------- exact fp32-replica rescan of near-tie rows (f64 dot) ----------
__global__ __launch_bounds__(256) void k_fix(const float* __restrict__ z,
                                             const float* __restrict__ emb,
                                             const float* __restrict__ szt,
                                             const int* __restrict__ list,
                                             const int* __restrict__ cnt,
                                             int* __restrict__ idx) {
  __shared__ double zd[FR][DIM];
  __shared__ float szr[FR];
  __shared__ float redD[FR][4];
  __shared__ int   redK[FR][4];
  const int tid = threadIdx.x;
  const int nf = *cnt;
  for (int base = blockIdx.x * FR; base < nf; base += gridDim.x * FR) {
    const int nr = min(FR, nf - base);
    for (int i = 0; i < nr; ++i) {
      int n = list[base + i];
      int b = n >> 11, l = n & (LSEQ - 1);
      zd[i][tid] = (double)z[(size_t)b * DIM * LSEQ + (size_t)tid * LSEQ + l];
    }
    if (tid < nr) szr[tid] = szt[list[base + tid]];
    __syncthreads();

    float bD[FR]; int bK[FR];
    #pragma unroll
    for (int i = 0; i < FR; ++i) { bD[i] = FLT_MAX; bK[i] = INT_MAX; }

    for (int kb = 0; kb < KCB / 256; ++kb) {
      int k = kb * 256 + tid;
      const float4* er4 = (const float4*)(emb + (size_t)k * DIM);
      double dot[FR];
      #pragma unroll
      for (int i = 0; i < FR; ++i) dot[i] = 0.0;
      for (int d4 = 0; d4 < DIM / 4; ++d4) {
        float4 e4 = er4[d4];
        int d = d4 * 4;
        double e0 = (double)e4.x, e1 = (double)e4.y, e2 = (double)e4.z, e3 = (double)e4.w;
        #pragma unroll
        for (int i = 0; i < FR; ++i) dot[i] = fma(e0, zd[i][d + 0], dot[i]);
        #pragma unroll
        for (int i = 0; i < FR; ++i) dot[i] = fma(e1, zd[i][d + 1], dot[i]);
        #pragma unroll
        for (int i = 0; i < FR; ++i) dot[i] = fma(e2, zd[i][d + 2], dot[i]);
        #pragma unroll
        for (int i = 0; i < FR; ++i) dot[i] = fma(e3, zd[i][d + 3], dot[i]);
      }
      #pragma unroll
      for (int i = 0; i < FR; ++i) {
        float D = __fsub_rn(szr[i], __fmul_rn(2.f, (float)dot[i]));
        if (D < bD[i] || (D == bD[i] && k < bK[i])) { bD[i] = D; bK[i] = k; }
      }
    }

    for (int i = 0; i < nr; ++i) {
      float D = bD[i]; int K = bK[i];
      #pragma unroll
      for (int off = 1; off < 64; off <<= 1) {
        float oD = __shfl_xor(D, off, 64);
        int   oK = __shfl_xor(K, off, 64);
        if (oD < D || (oD == D && oK < K)) { D = oD; K = oK; }
      }
      if ((tid & 63) == 0) { redD[i][tid >> 6] = D; redK[i][tid >> 6] = K; }
    }
    __syncthreads();
    if (tid < nr) {
      float D = redD[tid][0]; int K = redK[tid][0];
      #pragma unroll
      for (int ww = 1; ww < 4; ++ww)
        if (redD[tid][ww] < D || (redD[tid][ww] == D && redK[tid][ww] < K)) {
          D = redD[tid][ww]; K = redK[tid][ww];
        }
      idx[list[base + tid]] = K;
    }
    __syncthreads();
  }
}

// ---------- gather + loss partials ----------
__global__ __launch_bounds__(256) void k_gather(const float* __restrict__ z,
                                                const float* __restrict__ emb,
                                                const int* __restrict__ idx,
                                                float* __restrict__ zq_out,
                                                float* __restrict__ idxf_out,
                                                float* __restrict__ partial) {
  __shared__ int il[64];
  __shared__ float red[4];
  const int tid = threadIdx.x;
  const int n0 = blockIdx.x * 64;
  const int b = n0 >> 11, l0 = n0 & (LSEQ - 1);
  if (tid < 64) {
    int v = idx[n0 + tid];
    il[tid] = v;
    idxf_out[n0 + tid] = (float)v;
  }
  __syncthreads();
  const int dgrp = tid >> 6;
  const int lo   = tid & 63;
  const size_t zb = (size_t)b * DIM * LSEQ + l0 + lo;
  const int myidx = il[lo];
  float acc = 0.f;
  #pragma unroll 4
  for (int dd = 0; dd < 64; ++dd) {
    int d = dgrp + dd * 4;
    float e  = emb[(size_t)myidx * DIM + d];
    float zv = z[zb + (size_t)d * LSEQ];
    zq_out[zb + (size_t)d * LSEQ] = e;
    float df = e - zv;
    acc = fmaf(df, df, acc);
  }
  #pragma unroll
  for (int off = 1; off < 64; off <<= 1) acc += __shfl_xor(acc, off, 64);
  if ((tid & 63) == 0) red[tid >> 6] = acc;
  __syncthreads();
  if (tid == 0) partial[blockIdx.x] = red[0] + red[1] + red[2] + red[3];
}

__global__ __launch_bounds__(256) void k_loss(const float* __restrict__ partial,
                                              float* __restrict__ out_loss) {
  const int tid = threadIdx.x;
  double a = (double)partial[tid];
  #pragma unroll
  for (int off = 1; off < 64; off <<= 1) a += __shfl_xor(a, off, 64);
  __shared__ double r[4];
  if ((tid & 63) == 0) r[tid >> 6] = a;
  __syncthreads();
  if (tid == 0) {
    double s = r[0] + r[1] + r[2] + r[3];
    out_loss[0] = (float)(1.25 * s / (double)((size_t)N_TOT * DIM));
  }
}

extern "C" void kernel_launch(void* const* d_in, const int* in_sizes, int n_in,
                              void* d_out, int out_size, void* d_ws, size_t ws_size,
                              hipStream_t stream) {
  const float* z   = (const float*)d_in[0];
  const float* emb = (const float*)d_in[1];
  float* out = (float*)d_out;
  char* ws = (char*)d_ws;

  u16*   zhi  = (u16*)(ws + WS_ZT_HI);
  u16*   zlo  = (u16*)(ws + WS_ZT_LO);
  u16*   ehi  = (u16*)(ws + WS_E_HI);
  u16*   elo  = (u16*)(ws + WS_E_LO);
  float* sz   = (float*)(ws + WS_SZ);
  int*   idx  = (int*)(ws + WS_IDX);
  int*   flag = (int*)(ws + WS_FLAG);
  int*   list = (int*)(ws + WS_LIST);
  int*   cnt  = (int*)(ws + WS_CNT);
  float* part = (float*)(ws + WS_PART);
  float* pa1  = (float*)(ws + WS_PA1);
  float* pa2  = (float*)(ws + WS_PA2);
  int*   pi1  = (int*)(ws + WS_PI1);

  float* zq_out   = out;
  float* loss_out = out + (size_t)N_TOT * DIM;
  float* idxf_out = out + (size_t)N_TOT * DIM + 1;

  k_zero   <<<1,    1,   0, stream>>>(cnt);
  k_split_z<<<1024, 256, 0, stream>>>(z, zhi, zlo);
  k_split_e<<<2048, 256, 0, stream>>>(emb, ehi, elo);
  k_sz     <<<64,   256, 0, stream>>>(z, sz);
  k_mfma   <<<256,  512, 131072, stream>>>(zhi, zlo, ehi, elo, pa1, pa2, pi1);
  k_merge  <<<64,   256, 0, stream>>>(pa1, pa2, pi1, idx, flag);
  k_compact<<<64,   256, 0, stream>>>(flag, list, cnt);
  k_fix    <<<512,  256, 0, stream>>>(z, emb, sz, list, cnt, idx);
  k_gather <<<256,  256, 0, stream>>>(z, emb, idx, zq_out, idxf_out, part);
  k_loss   <<<1,    256, 0, stream>>>(part, loss_out);
}

// Round 4
// 453.258 us; speedup vs baseline: 5.1318x; 1.2229x over previous
//
#include <hip/hip_runtime.h>
#include <hip/hip_bf16.h>
#include <math.h>
#include <float.h>
#include <limits.h>

#define N_TOT   16384
#define DIM     256
#define KCB     8192
#define LSEQ    2048
#define TAU_A   1.8e-5f
#define W_SCAN  2.6e-5f

typedef unsigned short u16;
typedef unsigned int   u32;
typedef unsigned long long u64;
typedef __attribute__((ext_vector_type(8))) short bf16x8;
typedef __attribute__((ext_vector_type(4))) float f32x4;

// ws layout (bytes)
#define WS_ZT_HI 0u
#define WS_ZT_LO 8388608u
#define WS_E_HI  16777216u
#define WS_E_LO  20971520u
#define WS_SZ    25165824u
#define WS_IDX   25231360u
#define WS_FLAG  25296896u
#define WS_LIST  25362432u
#define WS_CNT   25427968u
#define WS_PART  25428992u
#define WS_PA1   25430016u
#define WS_PA2   25561088u
#define WS_PI1   25692160u
#define WS_A1M   25823232u
#define WS_RB    25888768u

__device__ __forceinline__ u16 f2bf_bits(float x) {
  __hip_bfloat16 h = __float2bfloat16(x);
  return *reinterpret_cast<u16*>(&h);
}
__device__ __forceinline__ float bfbits2f(u16 b) {
  __hip_bfloat16 h = *reinterpret_cast<__hip_bfloat16*>(&b);
  return __bfloat162float(h);
}

__device__ __forceinline__ void gl_lds16(const void* g, void* l) {
  __builtin_amdgcn_global_load_lds(
      (const __attribute__((address_space(1))) u32*)g,
      (__attribute__((address_space(3))) u32*)l, 16, 0, 0);
}

// ---------- split z [b][d][l] -> zt_hi/zt_lo [n][d] bf16 ----------
__global__ __launch_bounds__(256) void k_split_z(const float* __restrict__ z,
                                                 u16* __restrict__ zhi,
                                                 u16* __restrict__ zlo) {
  int bidx = blockIdx.x;                 // 8 b * 4 dt * 32 lt = 1024
  int lt = bidx & 31, dt = (bidx >> 5) & 3, bb = bidx >> 7;
  int ll = threadIdx.x & 63, dg = threadIdx.x >> 6;
  int l = lt * 64 + ll, d0 = dt * 64 + dg * 16;
  int n = bb * LSEQ + l;
  const float* zp = z + (size_t)bb * DIM * LSEQ + (size_t)d0 * LSEQ + l;
  u32 hw[8], lw[8];
  #pragma unroll
  for (int j = 0; j < 16; ++j) {
    float v = zp[(size_t)j * LSEQ];
    u16 hb = f2bf_bits(v);
    float hf = bfbits2f(hb);
    u16 lb = f2bf_bits(v - hf);
    if (j & 1) { hw[j >> 1] |= (u32)hb << 16; lw[j >> 1] |= (u32)lb << 16; }
    else       { hw[j >> 1]  = hb;            lw[j >> 1]  = lb; }
  }
  size_t o = (size_t)n * DIM + d0;
  *(uint4*)(zhi + o)     = make_uint4(hw[0], hw[1], hw[2], hw[3]);
  *(uint4*)(zhi + o + 8) = make_uint4(hw[4], hw[5], hw[6], hw[7]);
  *(uint4*)(zlo + o)     = make_uint4(lw[0], lw[1], lw[2], lw[3]);
  *(uint4*)(zlo + o + 8) = make_uint4(lw[4], lw[5], lw[6], lw[7]);
}

// ---------- split emb [k][d] -> e_hi/e_lo bf16 ----------
__global__ __launch_bounds__(256) void k_split_e(const float* __restrict__ emb,
                                                 u16* __restrict__ ehi,
                                                 u16* __restrict__ elo) {
  int g = blockIdx.x * 256 + threadIdx.x;   // 2048 blocks, 4 floats each
  float4 v = ((const float4*)emb)[g];
  u16 h0 = f2bf_bits(v.x), h1 = f2bf_bits(v.y), h2 = f2bf_bits(v.z), h3 = f2bf_bits(v.w);
  u16 l0 = f2bf_bits(v.x - bfbits2f(h0));
  u16 l1 = f2bf_bits(v.y - bfbits2f(h1));
  u16 l2 = f2bf_bits(v.z - bfbits2f(h2));
  u16 l3 = f2bf_bits(v.w - bfbits2f(h3));
  ((uint2*)ehi)[g] = make_uint2((u32)h0 | ((u32)h1 << 16), (u32)h2 | ((u32)h3 << 16));
  ((uint2*)elo)[g] = make_uint2((u32)l0 | ((u32)l1 << 16), (u32)l2 | ((u32)l3 << 16));
}

// ---------- np-replica fp32 pairwise row norms (verified) ----------
__global__ __launch_bounds__(256) void k_sz(const float* __restrict__ z,
                                            float* __restrict__ sz) {
  int n = blockIdx.x * 256 + threadIdx.x;
  int b = n >> 11, l = n & (LSEQ - 1);
  const float* zp = z + (size_t)b * DIM * LSEQ + l;
  float h[2];
  #pragma unroll
  for (int half = 0; half < 2; ++half) {
    int d0 = half * 128;
    float r[8];
    #pragma unroll
    for (int j = 0; j < 8; ++j) {
      float v = zp[(size_t)(d0 + j) * LSEQ];
      r[j] = __fmul_rn(v, v);
    }
    #pragma unroll
    for (int i = 8; i < 128; i += 8) {
      #pragma unroll
      for (int j = 0; j < 8; ++j) {
        float v = zp[(size_t)(d0 + i + j) * LSEQ];
        r[j] = __fadd_rn(r[j], __fmul_rn(v, v));
      }
    }
    h[half] = __fadd_rn(__fadd_rn(__fadd_rn(r[0], r[1]), __fadd_rn(r[2], r[3])),
                        __fadd_rn(__fadd_rn(r[4], r[5]), __fadd_rn(r[6], r[7])));
  }
  sz[n] = __fadd_rn(h[0], h[1]);
}

// ---------- MFMA top-2 phase-1 (validated round 3, unchanged) ----------
__global__ __launch_bounds__(512) void k_mfma(const u16* __restrict__ zhi_g,
                                              const u16* __restrict__ zlo_g,
                                              const u16* __restrict__ ehi_g,
                                              const u16* __restrict__ elo_g,
                                              float* __restrict__ pa1,
                                              float* __restrict__ pa2,
                                              int* __restrict__ pi1) {
  extern __shared__ char smem[];
  const int tid = threadIdx.x;
  const int lane = tid & 63, w = tid >> 6;
  const int wr = w >> 2, wc = w & 3;
  const int bid = blockIdx.x;
  const int half = bid & 1;
  const int rb = (bid >> 1) * 128;
  const size_t zrow0 = (size_t)rb * 512;
  const size_t ecol0 = (size_t)half * 4096 * 512;
  const int srcoff = ((lane >> 3) << 9) + ((((lane & 7) ^ ((lane >> 3) & 7))) << 4);
  const int arr = w >> 1;
  const char* gbase = (arr == 0) ? (const char*)zhi_g + zrow0
                    : (arr == 1) ? (const char*)zlo_g + zrow0
                    : (arr == 2) ? (const char*)ehi_g + ecol0
                                 : (const char*)elo_g + ecol0;
  const bool is_e = (arr >= 2);
  const int i0 = (w & 1) * 8;

  f32x4 acc[4][2];
  #pragma unroll
  for (int rc = 0; rc < 4; ++rc)
    #pragma unroll
    for (int cc = 0; cc < 2; ++cc) acc[rc][cc] = (f32x4){0.f, 0.f, 0.f, 0.f};

  float a1[4], a2[4]; int i1[4];
  #pragma unroll
  for (int rc = 0; rc < 4; ++rc) { a1[rc] = -FLT_MAX; a2[rc] = -FLT_MAX; i1[rc] = 0; }

  int rbyte[4], cbyte[2];
  #pragma unroll
  for (int rc = 0; rc < 4; ++rc) rbyte[rc] = (wr * 64 + rc * 16 + (lane & 15)) * 128;
  #pragma unroll
  for (int cc = 0; cc < 2; ++cc) cbyte[cc] = (wc * 32 + cc * 16 + (lane & 15)) * 128;

  #define STAGE(P) {                                                        \
    int dq_ = (P) & 3, t_ = (P) >> 2;                                       \
    char* buf_ = smem + (((P) & 1) << 16) + arr * 16384;                    \
    const char* s0_ = gbase + (is_e ? (size_t)t_ * 65536 : (size_t)0)       \
                            + dq_ * 128 + srcoff;                           \
    _Pragma("unroll")                                                       \
    for (int j_ = 0; j_ < 8; ++j_) {                                        \
      int i_ = i0 + j_;                                                     \
      gl_lds16(s0_ + (size_t)i_ * 4096, buf_ + i_ * 1024);                  \
    }                                                                       \
  }

  STAGE(0);
  __syncthreads();

  for (int p = 0; p < 128; ++p) {
    if (p + 1 < 128) STAGE(p + 1);
    const char* b0 = smem + ((p & 1) << 16);
    const char* bzh = b0;
    const char* bzl = b0 + 16384;
    const char* beh = b0 + 32768;
    const char* bel = b0 + 49152;
    #pragma unroll
    for (int kc = 0; kc < 2; ++kc) {
      int coff = ((kc * 4 + (lane >> 4)) ^ (lane & 7)) << 4;
      bf16x8 bh[4], bl[4], ah[2], al[2];
      #pragma unroll
      for (int rc = 0; rc < 4; ++rc) {
        bh[rc] = *(const bf16x8*)(bzh + rbyte[rc] + coff);
        bl[rc] = *(const bf16x8*)(bzl + rbyte[rc] + coff);
      }
      #pragma unroll
      for (int cc = 0; cc < 2; ++cc) {
        ah[cc] = *(const bf16x8*)(beh + cbyte[cc] + coff);
        al[cc] = *(const bf16x8*)(bel + cbyte[cc] + coff);
      }
      #pragma unroll
      for (int rc = 0; rc < 4; ++rc)
        #pragma unroll
        for (int cc = 0; cc < 2; ++cc) {
          acc[rc][cc] = __builtin_amdgcn_mfma_f32_16x16x32_bf16(ah[cc], bh[rc], acc[rc][cc], 0, 0, 0);
          acc[rc][cc] = __builtin_amdgcn_mfma_f32_16x16x32_bf16(ah[cc], bl[rc], acc[rc][cc], 0, 0, 0);
          acc[rc][cc] = __builtin_amdgcn_mfma_f32_16x16x32_bf16(al[cc], bh[rc], acc[rc][cc], 0, 0, 0);
        }
    }
    if ((p & 3) == 3) {
      int t = p >> 2;
      int cbase = half * 4096 + t * 128 + wc * 32 + (lane >> 4) * 4;
      #pragma unroll
      for (int rc = 0; rc < 4; ++rc)
        #pragma unroll
        for (int cc = 0; cc < 2; ++cc) {
          #pragma unroll
          for (int r = 0; r < 4; ++r) {
            float v = acc[rc][cc][r];
            int code = cbase + cc * 16 + r;
            if (v > a1[rc]) { a2[rc] = a1[rc]; a1[rc] = v; i1[rc] = code; }
            else            { a2[rc] = fmaxf(a2[rc], v); }
          }
          acc[rc][cc] = (f32x4){0.f, 0.f, 0.f, 0.f};
        }
    }
    __syncthreads();
  }
  #undef STAGE

  #pragma unroll
  for (int rc = 0; rc < 4; ++rc) {
    #pragma unroll
    for (int off = 16; off < 64; off <<= 1) {
      float o1 = __shfl_xor(a1[rc], off, 64);
      float o2 = __shfl_xor(a2[rc], off, 64);
      int   oi = __shfl_xor(i1[rc], off, 64);
      if (o1 > a1[rc] || (o1 == a1[rc] && oi < i1[rc])) {
        a2[rc] = fmaxf(a1[rc], o2); a1[rc] = o1; i1[rc] = oi;
      } else {
        a2[rc] = fmaxf(a2[rc], o1);
      }
    }
  }
  float* sa1 = (float*)smem;            // [4][128]
  float* sa2 = sa1 + 512;
  int*   si1 = (int*)(sa2 + 512);
  if ((lane >> 4) == 0) {
    #pragma unroll
    for (int rc = 0; rc < 4; ++rc) {
      int rl = wr * 64 + rc * 16 + lane;
      sa1[wc * 128 + rl] = a1[rc];
      sa2[wc * 128 + rl] = a2[rc];
      si1[wc * 128 + rl] = i1[rc];
    }
  }
  __syncthreads();
  if (tid < 128) {
    float g1 = sa1[tid], g2 = sa2[tid]; int gi = si1[tid];
    #pragma unroll
    for (int q = 1; q < 4; ++q) {
      float o1 = sa1[q * 128 + tid], o2 = sa2[q * 128 + tid]; int oi = si1[q * 128 + tid];
      if (o1 > g1 || (o1 == g1 && oi < gi)) { g2 = fmaxf(g1, o2); g1 = o1; gi = oi; }
      else { g2 = fmaxf(g2, o1); }
    }
    int n = rb + tid;
    pa1[half * N_TOT + n] = g1;
    pa2[half * N_TOT + n] = g2;
    pi1[half * N_TOT + n] = gi;
  }
}

__global__ void k_zero(int* cnt) { *cnt = 0; }

// ---------- merge halves; emit idx, a1m, flag, compacted list, rowbest init ----------
__global__ __launch_bounds__(256) void k_merge(const float* __restrict__ pa1,
                                               const float* __restrict__ pa2,
                                               const int* __restrict__ pi1,
                                               int* __restrict__ idx,
                                               int* __restrict__ flag,
                                               float* __restrict__ a1mo,
                                               u64* __restrict__ rowbest,
                                               int* __restrict__ list,
                                               int* __restrict__ cnt) {
  int n = blockIdx.x * 256 + threadIdx.x;
  float g1 = pa1[n], g2 = pa2[n]; int gi = pi1[n];
  float o1 = pa1[N_TOT + n], o2 = pa2[N_TOT + n]; int oi = pi1[N_TOT + n];
  if (o1 > g1 || (o1 == g1 && oi < gi)) { g2 = fmaxf(g1, o2); g1 = o1; gi = oi; }
  else { g2 = fmaxf(g2, o1); }
  idx[n] = gi;
  a1mo[n] = g1;
  rowbest[n] = 0xFFFFFFFFFFFFFFFFull;
  int f = (g1 - g2 < TAU_A) ? 1 : 0;
  flag[n] = f;
  if (f) { int p = atomicAdd(cnt, 1); list[p] = n; }
}

// ---------- certified fixup: f32 tiled rescan + inline f64 confirm ----------
// items = ceil(nf/32) groups x 8 code-splits of 1024. Per item: 32 rows x 1024
// codes; 8 code-tiles of 128 x 4 d-chunks of 64, reg-double-buffered LDS.
// Candidates (dot >= a1m - W_SCAN) get exact f64 dot -> D -> atomicMin key.
__global__ __launch_bounds__(256) void k_scan(const float* __restrict__ z,
                                              const float* __restrict__ emb,
                                              const float* __restrict__ szt,
                                              const float* __restrict__ a1m,
                                              const int* __restrict__ list,
                                              const int* __restrict__ cnt,
                                              u64* __restrict__ rowbest) {
  extern __shared__ char sm[];
  float (*zs)[260]     = (float(*)[260])sm;                    // 33280 B
  float (*et)[128][68] = (float(*)[128][68])(sm + 33280);      // 2x34816 B
  float* a1s = (float*)(sm + 33280 + 69632);
  float* szs = a1s + 32;
  int*   ns  = (int*)(szs + 32);
  const float4* emb4 = (const float4*)emb;
  const int tid = threadIdx.x;
  const int nf = *cnt;
  const int nitems = ((nf + 31) >> 5) << 3;
  const int cg = tid & 31, rgg = tid >> 5, swz = cg & 7;

  for (int item = blockIdx.x; item < nitems; item += gridDim.x) {
    int grp = item >> 3, sp = item & 7;
    {
      int r = tid >> 3, c8 = tid & 7;
      int gi = grp * 32 + r;
      if (gi < nf) {
        int n = list[gi];
        const float* zp = z + ((size_t)(n >> 11)) * DIM * LSEQ + (n & (LSEQ - 1));
        #pragma unroll 8
        for (int m = 0; m < 32; ++m) {
          int d = c8 * 32 + m;
          zs[r][d] = zp[(size_t)d * LSEQ];
        }
      }
      if (tid < 32) {
        int g2 = grp * 32 + tid;
        if (g2 < nf) {
          int n = list[g2];
          a1s[tid] = a1m[n]; szs[tid] = szt[n]; ns[tid] = n;
        } else {
          a1s[tid] = 3e38f;
        }
      }
    }
    __syncthreads();

    float4 pf[8];
    {   // preload stage 0
      int kb = sp * 1024;
      #pragma unroll
      for (int jj = 0; jj < 8; ++jj) {
        int g = tid + 256 * jj;
        pf[jj] = emb4[(size_t)(kb + (g >> 4)) * 64 + (g & 15)];
      }
    }
    float acc[4][4];
    #pragma unroll
    for (int i = 0; i < 4; ++i)
      #pragma unroll
      for (int j = 0; j < 4; ++j) acc[i][j] = 0.f;

    for (int s = 0; s < 32; ++s) {
      int buf = s & 1;
      #pragma unroll
      for (int jj = 0; jj < 8; ++jj) {
        int g = tid + 256 * jj;
        *(float4*)&et[buf][g >> 4][(g & 15) * 4] = pf[jj];
      }
      __syncthreads();
      if (s < 31) {
        int s1 = s + 1, ct_ = s1 >> 2, dc_ = s1 & 3;
        int kb = sp * 1024 + ct_ * 128;
        #pragma unroll
        for (int jj = 0; jj < 8; ++jj) {
          int g = tid + 256 * jj;
          pf[jj] = emb4[(size_t)(kb + (g >> 4)) * 64 + dc_ * 16 + (g & 15)];
        }
      }
      {
        int dc = s & 3;
        #pragma unroll 4
        for (int dk = 0; dk < 16; ++dk) {
          int dkx = dk ^ swz;
          float4 zz[4], ee[4];
          #pragma unroll
          for (int i = 0; i < 4; ++i)
            zz[i] = *(const float4*)&zs[4 * rgg + i][dc * 64 + dkx * 4];
          #pragma unroll
          for (int j = 0; j < 4; ++j)
            ee[j] = *(const float4*)&et[buf][4 * cg + j][dkx * 4];
          #pragma unroll
          for (int i = 0; i < 4; ++i)
            #pragma unroll
            for (int j = 0; j < 4; ++j) {
              acc[i][j] = fmaf(zz[i].x, ee[j].x, acc[i][j]);
              acc[i][j] = fmaf(zz[i].y, ee[j].y, acc[i][j]);
              acc[i][j] = fmaf(zz[i].z, ee[j].z, acc[i][j]);
              acc[i][j] = fmaf(zz[i].w, ee[j].w, acc[i][j]);
            }
        }
      }
      if ((s & 3) == 3) {
        int k0 = sp * 1024 + (s >> 2) * 128;
        #pragma unroll
        for (int i = 0; i < 4; ++i) {
          int lr = 4 * rgg + i;
          float thr = a1s[lr] - W_SCAN;
          #pragma unroll
          for (int j = 0; j < 4; ++j) {
            if (acc[i][j] >= thr) {
              int code = k0 + 4 * cg + j;
              double dot = 0.0;
              const float4* er4 = emb4 + (size_t)code * 64;
              for (int d4 = 0; d4 < 64; ++d4) {
                float4 e4 = er4[d4];
                const float* zr = &zs[lr][d4 * 4];
                dot = fma((double)e4.x, (double)zr[0], dot);
                dot = fma((double)e4.y, (double)zr[1], dot);
                dot = fma((double)e4.z, (double)zr[2], dot);
                dot = fma((double)e4.w, (double)zr[3], dot);
              }
              float D = __fsub_rn(szs[lr], __fmul_rn(2.f, (float)dot));
              u64 key = ((u64)__float_as_uint(D) << 32) | (u32)code;
              atomicMin(rowbest + ns[lr], key);
            }
            acc[i][j] = 0.f;
          }
        }
      }
    }
    __syncthreads();
  }
}

// ---------- gather + loss partials (resolves flagged idx from rowbest) ----------
__global__ __launch_bounds__(256) void k_gather(const float* __restrict__ z,
                                                const float* __restrict__ emb,
                                                const int* __restrict__ idx,
                                                const int* __restrict__ flag,
                                                const u64* __restrict__ rowbest,
                                                float* __restrict__ zq_out,
                                                float* __restrict__ idxf_out,
                                                float* __restrict__ partial) {
  __shared__ int il[64];
  __shared__ float red[4];
  const int tid = threadIdx.x;
  const int n0 = blockIdx.x * 64;
  const int b = n0 >> 11, l0 = n0 & (LSEQ - 1);
  if (tid < 64) {
    int n = n0 + tid;
    int v = idx[n];
    if (flag[n]) {
      u64 rb = rowbest[n];
      if (rb != 0xFFFFFFFFFFFFFFFFull) v = (int)(rb & 0xFFFFFFFFu);
    }
    il[tid] = v;
    idxf_out[n] = (float)v;
  }
  __syncthreads();
  const int dgrp = tid >> 6;
  const int lo   = tid & 63;
  const size_t zb = (size_t)b * DIM * LSEQ + l0 + lo;
  const int myidx = il[lo];
  float acc = 0.f;
  #pragma unroll 4
  for (int dd = 0; dd < 64; ++dd) {
    int d = dgrp + dd * 4;
    float e  = emb[(size_t)myidx * DIM + d];
    float zv = z[zb + (size_t)d * LSEQ];
    zq_out[zb + (size_t)d * LSEQ] = e;
    float df = e - zv;
    acc = fmaf(df, df, acc);
  }
  #pragma unroll
  for (int off = 1; off < 64; off <<= 1) acc += __shfl_xor(acc, off, 64);
  if ((tid & 63) == 0) red[tid >> 6] = acc;
  __syncthreads();
  if (tid == 0) partial[blockIdx.x] = red[0] + red[1] + red[2] + red[3];
}

__global__ __launch_bounds__(256) void k_loss(const float* __restrict__ partial,
                                              float* __restrict__ out_loss) {
  const int tid = threadIdx.x;
  double a = (double)partial[tid];
  #pragma unroll
  for (int off = 1; off < 64; off <<= 1) a += __shfl_xor(a, off, 64);
  __shared__ double r[4];
  if ((tid & 63) == 0) r[tid >> 6] = a;
  __syncthreads();
  if (tid == 0) {
    double s = r[0] + r[1] + r[2] + r[3];
    out_loss[0] = (float)(1.25 * s / (double)((size_t)N_TOT * DIM));
  }
}

extern "C" void kernel_launch(void* const* d_in, const int* in_sizes, int n_in,
                              void* d_out, int out_size, void* d_ws, size_t ws_size,
                              hipStream_t stream) {
  const float* z   = (const float*)d_in[0];
  const float* emb = (const float*)d_in[1];
  float* out = (float*)d_out;
  char* ws = (char*)d_ws;

  u16*   zhi  = (u16*)(ws + WS_ZT_HI);
  u16*   zlo  = (u16*)(ws + WS_ZT_LO);
  u16*   ehi  = (u16*)(ws + WS_E_HI);
  u16*   elo  = (u16*)(ws + WS_E_LO);
  float* sz   = (float*)(ws + WS_SZ);
  int*   idx  = (int*)(ws + WS_IDX);
  int*   flag = (int*)(ws + WS_FLAG);
  int*   list = (int*)(ws + WS_LIST);
  int*   cnt  = (int*)(ws + WS_CNT);
  float* part = (float*)(ws + WS_PART);
  float* pa1  = (float*)(ws + WS_PA1);
  float* pa2  = (float*)(ws + WS_PA2);
  int*   pi1  = (int*)(ws + WS_PI1);
  float* a1m  = (float*)(ws + WS_A1M);
  u64*   rb   = (u64*)(ws + WS_RB);

  float* zq_out   = out;
  float* loss_out = out + (size_t)N_TOT * DIM;
  float* idxf_out = out + (size_t)N_TOT * DIM + 1;

  k_zero   <<<1,    1,   0, stream>>>(cnt);
  k_split_z<<<1024, 256, 0, stream>>>(z, zhi, zlo);
  k_split_e<<<2048, 256, 0, stream>>>(emb, ehi, elo);
  k_sz     <<<64,   256, 0, stream>>>(z, sz);
  k_mfma   <<<256,  512, 131072, stream>>>(zhi, zlo, ehi, elo, pa1, pa2, pi1);
  k_merge  <<<64,   256, 0, stream>>>(pa1, pa2, pi1, idx, flag, a1m, rb, list, cnt);
  k_scan   <<<256,  256, 103424, stream>>>(z, emb, sz, a1m, list, cnt, rb);
  k_gather <<<256,  256, 0, stream>>>(z, emb, idx, flag, rb, zq_out, idxf_out, part);
  k_loss   <<<1,    256, 0, stream>>>(part, loss_out);
}